// Round 15
// baseline (833.010 us; speedup 1.0000x reference)
//
#include <hip/hip_runtime.h>

// Sinkhorn EMD, B=8, N=2048, eps=0.005, 50 iters.
// R15: one global stage per sparse iteration (not two).
//  - f-pass: plain gather of g^{t-1} (barrier-fresh, no polls), publish
//    f^t as (tag,value) uint64 to IC.
//  - g-pass: per-candidate POLL on f-tags (== t) instead of a barrier,
//    then publish g^t into parity slot gp2[t&1]; ONE barrier per iter.
//  - parity double-buffer makes write-after-read on g impossible (proof:
//    g^{t+1} is post-barrier(t), barrier(t) waits all g^t, g^t waits all
//    needed f^t via polls, f^t happens after reading g^{t-1}).
//  - build iterations (t=4,16,28,40) keep 2 barriers (dense sweeps).
// Base structure = R12 (best: 604us): register row state, per-row
// gathers, IC-coherent ops, distributed-arrival barrier (R13),
// online iters 1-3 dense with per-pass barrier, MARGIN=48, CAP=256.

#define BB 8
#define NN 2048
#define RPW 4
#define GRID_BLOCKS 256
#define TPB 1024
#define CAP 256
#define MARGIN 48.0f

typedef unsigned long long ull;

constexpr float EPSV = 0.005f;
constexpr float KS   = EPSV * 0.69314718055994531f; // eps*ln2
constexpr float INVK = 1.0f / KS;
constexpr float C1V  = -EPSV * 7.6246189861593985f; // eps*log(1/2048)
constexpr float C1K  = C1V * INVK;
constexpr float KQ4  = KS * 0.25f;
constexpr float TWOI = 2.0f * INVK;
constexpr float HK   = KS * 0.5f;

__device__ __forceinline__ float fexp2(float x) { return __builtin_amdgcn_exp2f(x); }
__device__ __forceinline__ float flog2(float x) { return __builtin_amdgcn_logf(x); }

__device__ __forceinline__ float cohLoad(const float* p) {
    return __hip_atomic_load(p, __ATOMIC_RELAXED, __HIP_MEMORY_SCOPE_AGENT);
}
__device__ __forceinline__ void cohStore(float* p, float v) {
    __hip_atomic_store(p, v, __ATOMIC_RELAXED, __HIP_MEMORY_SCOPE_AGENT);
}
__device__ __forceinline__ int cohLoadI(const int* p) {
    return __hip_atomic_load(p, __ATOMIC_RELAXED, __HIP_MEMORY_SCOPE_AGENT);
}
__device__ __forceinline__ void cohStoreI(int* p, int v) {
    __hip_atomic_store(p, v, __ATOMIC_RELAXED, __HIP_MEMORY_SCOPE_AGENT);
}
__device__ __forceinline__ ull cohLoad64(const ull* p) {
    return __hip_atomic_load(p, __ATOMIC_RELAXED, __HIP_MEMORY_SCOPE_AGENT);
}
__device__ __forceinline__ void cohStore64(ull* p, ull v) {
    __hip_atomic_store(p, v, __ATOMIC_RELAXED, __HIP_MEMORY_SCOPE_AGENT);
}
__device__ __forceinline__ ull packTV(unsigned tag, float v) {
    return ((ull)tag << 32) | (ull)__float_as_uint(v);
}

// distributed-arrival barrier (R13)
__device__ __forceinline__ void barrier_sync(int* arr, int rb, int target) {
    __syncthreads();
    if (threadIdx.x < 64) {
        if (threadIdx.x == 0) cohStoreI(&arr[rb], target);
        const int slot = threadIdx.x & 31;
        while (true) {
            int v = cohLoadI(&arr[slot]);
            if (__ballot(v >= target) == ~0ull) break;
            __builtin_amdgcn_s_sleep(1);
        }
    }
    __syncthreads();
}

__device__ __forceinline__ void barrier_ctr(int* ctr, int target) {
    __syncthreads();
    if (threadIdx.x == 0) {
        __hip_atomic_fetch_add(ctr, 1, __ATOMIC_RELAXED, __HIP_MEMORY_SCOPE_AGENT);
        while (__hip_atomic_load(ctr, __ATOMIC_RELAXED, __HIP_MEMORY_SCOPE_AGENT) < target) {
            __builtin_amdgcn_s_sleep(1);
        }
    }
    __syncthreads();
}

__global__ void __launch_bounds__(TPB, 4) emd_persist(
    const float* __restrict__ preds, const float* __restrict__ gts,
    float* __restrict__ fpot, float* __restrict__ gpot,
    ull* __restrict__ fTag, float* __restrict__ gp2,
    float* __restrict__ partials, int* __restrict__ barArr, int* __restrict__ gctr,
    float* __restrict__ out)
{
    __shared__ float4 sjall[2 * NN];
    __shared__ float  sa[NN];
    __shared__ float  wred[16];
    __shared__ unsigned short slist[2][64][CAP];

    const int blk  = blockIdx.x;
    const int b    = blk & 7;
    const int rb   = blk >> 3;
    const int wave = threadIdx.x >> 6;
    const int lane = threadIdx.x & 63;
    const int rowL0 = wave * RPW;
    const int row0  = rb * 64 + rowL0;

    const float* pb  = preds + (size_t)b * NN * 3;
    const float* gbp = gts   + (size_t)b * NN * 3;
    float* fb   = fpot + (size_t)b * NN;
    float* gb   = gpot + (size_t)b * NN;
    ull*   fTb  = fTag + (size_t)b * NN;
    float* g2s0 = gp2 + (size_t)b * NN;            // parity 0
    float* g2s1 = gp2 + (size_t)(BB + b) * NN;     // parity 1
    int*   bar  = barArr + b * 64;
    int    bno  = 0;

    for (int t = threadIdx.x; t < NN; t += TPB) {
        float gx = gbp[3*t], gy = gbp[3*t+1], gz = gbp[3*t+2];
        float Gx = gx*TWOI, Gy = gy*TWOI, Gz = gz*TWOI;
        sjall[t] = make_float4(Gx, Gy, Gz, -KQ4*(Gx*Gx+Gy*Gy+Gz*Gz));
        float qx = pb[3*t], qy = pb[3*t+1], qz = pb[3*t+2];
        float Qx = qx*TWOI, Qy = qy*TWOI, Qz = qz*TWOI;
        sjall[NN+t] = make_float4(Qx, Qy, Qz, -KQ4*(Qx*Qx+Qy*Qy+Qz*Qz));
    }
    __syncthreads();

    float qxf[RPW], qyf[RPW], qzf[RPW], pcf[RPW];
    float qxg[RPW], qyg[RPW], qzg[RPW], pcg[RPW];
#pragma unroll
    for (int r = 0; r < RPW; ++r) {
        float4 df = sjall[NN + row0 + r];
        qxf[r] = HK*df.x; qyf[r] = HK*df.y; qzf[r] = HK*df.z;
        pcf[r] = C1V - KS*df.w;
        float4 dg = sjall[row0 + r];
        qxg[r] = HK*dg.x; qyg[r] = HK*dg.y; qzg[r] = HK*dg.z;
        pcg[r] = C1V - KS*dg.w;
    }
    float LpF[RPW] = {0,0,0,0}, LpG[RPW] = {0,0,0,0};
    int   cnF[RPW] = {0,0,0,0}, cnG[RPW] = {0,0,0,0};

    // ---------- online iterations 1..3 (passes 0..5), barrier per pass ----------
#pragma unroll 1
    for (int pass = 0; pass < 6; ++pass) {
        const int odd = pass & 1;
        const int colOff = odd ? NN : 0;
        const float* pin  = odd ? fb : gb;
        float*       pout = odd ? gb : fb;

        for (int t = threadIdx.x; t < NN; t += TPB)
            sa[t] = cohLoad(&pin[t]) * INVK;

        float qx[RPW], qy[RPW], qz[RPW], pc[RPW];
#pragma unroll
        for (int r = 0; r < RPW; ++r) {
            qx[r] = odd ? qxg[r] : qxf[r];
            qy[r] = odd ? qyg[r] : qyf[r];
            qz[r] = odd ? qzg[r] : qzf[r];
            pc[r] = odd ? pcg[r] : pcf[r];
        }
        __syncthreads();

        float m[RPW], s[RPW];
#pragma unroll
        for (int r = 0; r < RPW; ++r) { m[r] = -1e30f; s[r] = 0.f; }
#pragma unroll 2
        for (int c = 0; c < 32; ++c) {
            float4 d = sjall[colOff + c*64 + lane];
            float aw = d.w + sa[c*64 + lane];
#pragma unroll
            for (int r = 0; r < RPW; ++r) {
                float x  = fmaf(qx[r], d.x, fmaf(qy[r], d.y, fmaf(qz[r], d.z, aw)));
                float mn = fmaxf(m[r], x);
                s[r] = fmaf(s[r], fexp2(m[r]-mn), fexp2(x-mn));
                m[r] = mn;
            }
        }
#pragma unroll
        for (int r = 0; r < RPW; ++r) {
            float mm = m[r], sv = s[r];
            for (int off = 1; off < 64; off <<= 1) {
                float mo = __shfl_xor(mm, off, 64);
                float so = __shfl_xor(sv, off, 64);
                float mn = fmaxf(mm, mo);
                sv = fmaf(sv, fexp2(mm-mn), so * fexp2(mo-mn));
                mm = mn;
            }
            float L = mm + flog2(fmaxf(sv, 1e-37f));
            if (odd) LpG[r] = L; else LpF[r] = L;
            if (lane == 0) {
                float pot = pc[r] - KS * L;
                cohStore(&pout[row0 + r], pot);
                if (pass == 5) cohStore(&g2s1[row0 + r], pot); // seed parity (3&1)=1
            }
        }
        barrier_sync(bar, rb, ++bno);
    }

    // ---------- fused iterations t = 4..50 ----------
#pragma unroll 1
    for (int t = 4; t <= 50; ++t) {
        const bool build = (t == 4) || (t == 16) || (t == 28) || (t == 40);
        float* gRead  = ((t-1) & 1) ? g2s1 : g2s0;
        float* gWrite = (t & 1) ? g2s1 : g2s0;
        const unsigned wantT = (unsigned)t;

        if (build) {
            // ---- f build: stage + dense sweep + compaction ----
            for (int j = threadIdx.x; j < NN; j += TPB)
                sa[j] = cohLoad(&gRead[j]) * INVK;
            __syncthreads();
            float s[RPW]; int cn[RPW];
#pragma unroll
            for (int r = 0; r < RPW; ++r) { s[r] = 0.f; cn[r] = 0; }
#pragma unroll 1
            for (int c = 0; c < 32; ++c) {
                int j = c*64 + lane;
                float4 d = sjall[j];
                float aw = d.w + sa[j];
#pragma unroll
                for (int r = 0; r < RPW; ++r) {
                    float x = fmaf(qxf[r], d.x, fmaf(qyf[r], d.y, fmaf(qzf[r], d.z, aw)));
                    s[r] += fexp2(fminf(x - LpF[r], 100.f));
                    bool pred = (x >= LpF[r] - MARGIN);
                    unsigned long long mask = __ballot((int)pred);
                    if (pred) {
                        int pos = cn[r] + __popcll(mask & ((1ull << lane) - 1ull));
                        if (pos < CAP) slist[0][rowL0 + r][pos] = (unsigned short)j;
                    }
                    cn[r] += __popcll(mask);
                }
            }
#pragma unroll
            for (int r = 0; r < RPW; ++r) {
                float sv = s[r];
                for (int off = 1; off < 64; off <<= 1) sv += __shfl_xor(sv, off, 64);
                float L = LpF[r] + flog2(fmaxf(sv, 1e-37f));
                LpF[r] = L; cnF[r] = cn[r];
                if (lane == 0)
                    cohStore64(&fTb[row0 + r], packTV(wantT, pcf[r] - KS * L));
            }
            barrier_sync(bar, rb, ++bno);

            // ---- g build: stage from fTag + dense sweep + compaction ----
            for (int j = threadIdx.x; j < NN; j += TPB)
                sa[j] = __uint_as_float((unsigned)cohLoad64(&fTb[j])) * INVK;
            __syncthreads();
#pragma unroll
            for (int r = 0; r < RPW; ++r) { s[r] = 0.f; cn[r] = 0; }
#pragma unroll 1
            for (int c = 0; c < 32; ++c) {
                int j = c*64 + lane;
                float4 d = sjall[NN + j];
                float aw = d.w + sa[j];
#pragma unroll
                for (int r = 0; r < RPW; ++r) {
                    float x = fmaf(qxg[r], d.x, fmaf(qyg[r], d.y, fmaf(qzg[r], d.z, aw)));
                    s[r] += fexp2(fminf(x - LpG[r], 100.f));
                    bool pred = (x >= LpG[r] - MARGIN);
                    unsigned long long mask = __ballot((int)pred);
                    if (pred) {
                        int pos = cn[r] + __popcll(mask & ((1ull << lane) - 1ull));
                        if (pos < CAP) slist[1][rowL0 + r][pos] = (unsigned short)j;
                    }
                    cn[r] += __popcll(mask);
                }
            }
#pragma unroll
            for (int r = 0; r < RPW; ++r) {
                float sv = s[r];
                for (int off = 1; off < 64; off <<= 1) sv += __shfl_xor(sv, off, 64);
                float L = LpG[r] + flog2(fmaxf(sv, 1e-37f));
                LpG[r] = L; cnG[r] = cn[r];
                if (lane == 0)
                    cohStore(&gWrite[row0 + r], pcg[r] - KS * L);
            }
            barrier_sync(bar, rb, ++bno);
        } else {
            // ---- sparse f: plain gather (gRead barrier-fresh) ----
#pragma unroll
            for (int r = 0; r < RPW; ++r) {
                const int cnt = cnF[r];
                const unsigned short* lb = slist[0][rowL0 + r];
                float s1 = 0.f;
                if (cnt <= CAP) {
#pragma unroll 1
                    for (int k = lane; k < cnt; k += 64) {
                        int j = lb[k];
                        float4 d = sjall[j];
                        float aw = fmaf(cohLoad(&gRead[j]), INVK, d.w);
                        float x  = fmaf(qxf[r], d.x, fmaf(qyf[r], d.y, fmaf(qzf[r], d.z, aw)));
                        s1 += fexp2(fminf(x - LpF[r], 100.f));
                    }
                } else {
#pragma unroll 1
                    for (int c = 0; c < 32; ++c) {
                        int j = c*64 + lane;
                        float4 d = sjall[j];
                        float aw = fmaf(cohLoad(&gRead[j]), INVK, d.w);
                        float x  = fmaf(qxf[r], d.x, fmaf(qyf[r], d.y, fmaf(qzf[r], d.z, aw)));
                        s1 += fexp2(fminf(x - LpF[r], 100.f));
                    }
                }
                for (int off = 1; off < 64; off <<= 1) s1 += __shfl_xor(s1, off, 64);
                float L = LpF[r] + flog2(fmaxf(s1, 1e-37f));
                LpF[r] = L;
                if (lane == 0)
                    cohStore64(&fTb[row0 + r], packTV(wantT, pcf[r] - KS * L));
            }

            // ---- sparse g: poll-gather f^t by tag (no barrier before) ----
#pragma unroll
            for (int r = 0; r < RPW; ++r) {
                const int cnt = cnG[r];
                const unsigned short* lb = slist[1][rowL0 + r];
                float s1 = 0.f;
                if (cnt <= CAP) {
#pragma unroll 1
                    for (int k = lane; k < cnt; k += 64) {
                        int j = lb[k];
                        ull pv = cohLoad64(&fTb[j]);
                        while (__any((int)((unsigned)(pv >> 32) < wantT))) {
                            if ((unsigned)(pv >> 32) < wantT) pv = cohLoad64(&fTb[j]);
                        }
                        float4 d = sjall[NN + j];
                        float aw = fmaf(__uint_as_float((unsigned)pv), INVK, d.w);
                        float x  = fmaf(qxg[r], d.x, fmaf(qyg[r], d.y, fmaf(qzg[r], d.z, aw)));
                        s1 += fexp2(fminf(x - LpG[r], 100.f));
                    }
                } else {
#pragma unroll 1
                    for (int c = 0; c < 32; ++c) {
                        int j = c*64 + lane;
                        ull pv = cohLoad64(&fTb[j]);
                        while (__any((int)((unsigned)(pv >> 32) < wantT))) {
                            if ((unsigned)(pv >> 32) < wantT) pv = cohLoad64(&fTb[j]);
                        }
                        float4 d = sjall[NN + j];
                        float aw = fmaf(__uint_as_float((unsigned)pv), INVK, d.w);
                        float x  = fmaf(qxg[r], d.x, fmaf(qyg[r], d.y, fmaf(qzg[r], d.z, aw)));
                        s1 += fexp2(fminf(x - LpG[r], 100.f));
                    }
                }
                for (int off = 1; off < 64; off <<= 1) s1 += __shfl_xor(s1, off, 64);
                float L = LpG[r] + flog2(fmaxf(s1, 1e-37f));
                LpG[r] = L;
                if (lane == 0)
                    cohStore(&gWrite[row0 + r], pcg[r] - KS * L);
            }
            barrier_sync(bar, rb, ++bno);
        }
    }

    // ---------- dis: gather g^50 (parity 0, barrier-fresh) over f-lists ----------
    {
        float tot = 0.f;
#pragma unroll
        for (int r = 0; r < RPW; ++r) {
            const int cnt = cnF[r];
            const unsigned short* lb = slist[0][rowL0 + r];
            const float bb2 = C1K - LpF[r];
            const float pn  = pcf[r] - C1V;
            float aa = 0.f;
            if (cnt <= CAP) {
#pragma unroll 1
                for (int k = lane; k < cnt; k += 64) {
                    int j = lb[k];
                    float4 d = sjall[j];
                    float aw = fmaf(cohLoad(&g2s0[j]), INVK, d.w);
                    float dot = fmaf(qxf[r], d.x, fmaf(qyf[r], d.y, qzf[r]*d.z));
                    float y   = dot + aw + bb2;
                    float e   = fexp2(fminf(y, 80.f));
                    aa = fmaf(e, fmaf(-KS, dot, pn - KS*d.w), aa);
                }
            } else {
#pragma unroll 1
                for (int c = 0; c < 32; ++c) {
                    int j = c*64 + lane;
                    float4 d = sjall[j];
                    float aw = fmaf(cohLoad(&g2s0[j]), INVK, d.w);
                    float dot = fmaf(qxf[r], d.x, fmaf(qyf[r], d.y, qzf[r]*d.z));
                    float y   = dot + aw + bb2;
                    float e   = fexp2(fminf(y, 80.f));
                    aa = fmaf(e, fmaf(-KS, dot, pn - KS*d.w), aa);
                }
            }
            tot += aa;
        }
        for (int off = 1; off < 64; off <<= 1) tot += __shfl_xor(tot, off, 64);
        if (lane == 0) wred[wave] = tot;
        __syncthreads();
        if (threadIdx.x == 0) {
            float v = 0.f;
            for (int w = 0; w < 16; ++w) v += wred[w];
            cohStore(&partials[blk], v);
        }
    }

    barrier_ctr(gctr, GRID_BLOCKS);

    if (blk == 0) {
        float v = (threadIdx.x < GRID_BLOCKS) ? cohLoad(&partials[threadIdx.x]) : 0.f;
        for (int off = 1; off < 64; off <<= 1) v += __shfl_xor(v, off, 64);
        if (lane == 0) wred[wave] = v;
        __syncthreads();
        if (threadIdx.x == 0) {
            float t2 = 0.f;
            for (int w = 0; w < 16; ++w) t2 += wred[w];
            out[0] = t2 * (1.0f / BB);
        }
    }
}

extern "C" void kernel_launch(void* const* d_in, const int* in_sizes, int n_in,
                              void* d_out, int out_size, void* d_ws, size_t ws_size,
                              hipStream_t stream) {
    const float* preds = (const float*)d_in[0];
    const float* gts   = (const float*)d_in[1];
    ull*   fT       = (ull*)d_ws;                      // [B*N] tagged f
    float* gp2      = (float*)(fT + BB * NN);          // [2][B*N] parity g
    float* fp       = gp2 + 2 * BB * NN;               // [B*N] online f
    float* gp       = fp + BB * NN;                    // [B*N] online g
    float* partials = gp + BB * NN;                    // [256]
    int*   barArr   = (int*)(partials + GRID_BLOCKS);  // 8 x 64
    int*   gctr     = barArr + BB * 64;                // [32]
    float* out      = (float*)d_out;

    size_t zbytes = (size_t)(BB * NN) * sizeof(ull)
                  + (size_t)(4 * BB * NN + GRID_BLOCKS) * sizeof(float)
                  + (size_t)(BB * 64 + 32) * sizeof(int);
    hipMemsetAsync(d_ws, 0, zbytes, stream);

    emd_persist<<<dim3(GRID_BLOCKS), dim3(TPB), 0, stream>>>(
        preds, gts, fp, gp, fT, gp2, partials, barArr, gctr, out);
}

// Round 16
// 545.615 us; speedup vs baseline: 1.5267x; 1.5267x over previous
//
#include <hip/hip_runtime.h>

// Sinkhorn EMD, B=8, N=2048, eps=0.005, 50 iters.
// R16 = R12 (champion, 604us) with a cheaper pass-type schedule:
//  - online exact-LSE passes 0..3 (was 0..5): fixed-shift staircase
//    (clamp +100, floored sum) absorbs early drift, validated since R3.
//  - builds at {4,5} and one mid-course refresh {52,53} (was every 24):
//    drift budget = MARGIN(48) - f32 mantissa(24) = 24 log2 units
//    ~ 0.083 potential units over the 48-pass gap vs measured << 0.01.
// Everything else byte-identical to R12: register-resident row state,
// per-row sparse gathers w/ direct IC pot loads, counter barrier,
// IC-coherent ops no fences (R6), fully-unrolled r-state (R8),
// MARGIN=48, CAP=256 (R9). R13/R14/R15 mechanism changes all measured
// neutral-or-worse and are excluded.

#define BB 8
#define NN 2048
#define NPASS 100
#define ONLINE_PASSES 4
#define RPW 4
#define GRID_BLOCKS 256
#define BLOCKS_PER_BATCH 32
#define TPB 1024
#define CAP 256
#define MARGIN 48.0f

constexpr float EPSV = 0.005f;
constexpr float KS   = EPSV * 0.69314718055994531f; // eps*ln2
constexpr float INVK = 1.0f / KS;
constexpr float C1V  = -EPSV * 7.6246189861593985f; // eps*log(1/2048)
constexpr float C1K  = C1V * INVK;
constexpr float KQ4  = KS * 0.25f;
constexpr float TWOI = 2.0f * INVK;
constexpr float HK   = KS * 0.5f;

__device__ __forceinline__ float fexp2(float x) { return __builtin_amdgcn_exp2f(x); }
__device__ __forceinline__ float flog2(float x) { return __builtin_amdgcn_logf(x); }

__device__ __forceinline__ float cohLoad(const float* p) {
    return __hip_atomic_load(p, __ATOMIC_RELAXED, __HIP_MEMORY_SCOPE_AGENT);
}
__device__ __forceinline__ void cohStore(float* p, float v) {
    __hip_atomic_store(p, v, __ATOMIC_RELAXED, __HIP_MEMORY_SCOPE_AGENT);
}

__device__ __forceinline__ void barrier_sync(int* ctr, int target) {
    __syncthreads();   // drains vmcnt: all waves' cohStores acked at IC
    if (threadIdx.x == 0) {
        __hip_atomic_fetch_add(ctr, 1, __ATOMIC_RELAXED, __HIP_MEMORY_SCOPE_AGENT);
        while (__hip_atomic_load(ctr, __ATOMIC_RELAXED, __HIP_MEMORY_SCOPE_AGENT) < target) {
            __builtin_amdgcn_s_sleep(1);
        }
    }
    __syncthreads();
}

__global__ void __launch_bounds__(TPB, 4) emd_persist(
    const float* __restrict__ preds, const float* __restrict__ gts,
    float* __restrict__ fpot, float* __restrict__ gpot,
    float* __restrict__ partials, int* __restrict__ bctr, int* __restrict__ gctr,
    float* __restrict__ out)
{
    __shared__ float4 sjall[2 * NN];          // side0=gts, side1=preds
    __shared__ float  sa[NN];                 // staged pots (dense passes only)
    __shared__ float  wred[16];
    __shared__ unsigned short slist[2][64][CAP];

    const int blk  = blockIdx.x;
    const int b    = blk & 7;
    const int rb   = blk >> 3;
    const int wave = threadIdx.x >> 6;
    const int lane = threadIdx.x & 63;
    const int rowL0 = wave * RPW;             // 0..60
    const int row0  = rb * 64 + rowL0;        // global row base for this wave

    const float* pb  = preds + (size_t)b * NN * 3;
    const float* gbp = gts   + (size_t)b * NN * 3;
    float* fb = fpot + (size_t)b * NN;
    float* gb = gpot + (size_t)b * NN;
    int*   bar = bctr + b * 32;

    for (int t = threadIdx.x; t < NN; t += TPB) {
        float gx = gbp[3*t], gy = gbp[3*t+1], gz = gbp[3*t+2];
        float Gx = gx*TWOI, Gy = gy*TWOI, Gz = gz*TWOI;
        sjall[t] = make_float4(Gx, Gy, Gz, -KQ4*(Gx*Gx+Gy*Gy+Gz*Gz));
        float qx = pb[3*t], qy = pb[3*t+1], qz = pb[3*t+2];
        float Qx = qx*TWOI, Qy = qy*TWOI, Qz = qz*TWOI;
        sjall[NN+t] = make_float4(Qx, Qy, Qz, -KQ4*(Qx*Qx+Qy*Qy+Qz*Qz));
    }
    __syncthreads();

    // wave-resident row constants, both sides (loaded ONCE)
    float qxf[RPW], qyf[RPW], qzf[RPW], pcf[RPW];
    float qxg[RPW], qyg[RPW], qzg[RPW], pcg[RPW];
#pragma unroll
    for (int r = 0; r < RPW; ++r) {
        float4 df = sjall[NN + row0 + r];     // preds rows (f side)
        qxf[r] = HK*df.x; qyf[r] = HK*df.y; qzf[r] = HK*df.z;
        pcf[r] = C1V - KS*df.w;
        float4 dg = sjall[row0 + r];          // gts rows (g side)
        qxg[r] = HK*dg.x; qyg[r] = HK*dg.y; qzg[r] = HK*dg.z;
        pcg[r] = C1V - KS*dg.w;
    }
    float LpF[RPW] = {0,0,0,0}, LpG[RPW] = {0,0,0,0};
    int   cnF[RPW] = {0,0,0,0}, cnG[RPW] = {0,0,0,0};

#pragma unroll 1
    for (int pass = 0; pass < NPASS; ++pass) {
        const int odd = pass & 1;
        const int colOff = odd ? NN : 0;
        const float* pin  = odd ? fb : gb;
        float*       pout = odd ? gb : fb;
        const bool isBuild  = (pass == 4) || (pass == 5) ||
                              (pass == 52) || (pass == 53);
        const bool isSparse = (pass >= ONLINE_PASSES) && !isBuild;

        float qx[RPW], qy[RPW], qz[RPW], pc[RPW], M[RPW];
#pragma unroll
        for (int r = 0; r < RPW; ++r) {
            qx[r] = odd ? qxg[r] : qxf[r];
            qy[r] = odd ? qyg[r] : qyf[r];
            qz[r] = odd ? qzg[r] : qzf[r];
            pc[r] = odd ? pcg[r] : pcf[r];
            M[r]  = odd ? LpG[r] : LpF[r];
        }

        if (isSparse) {
            // ---- sparse: no staging, no intra-pass sync ----
            float L[RPW];
#pragma unroll
            for (int r = 0; r < RPW; ++r) {
                const int cnt = odd ? cnG[r] : cnF[r];
                const unsigned short* lb = slist[odd][rowL0 + r];
                float s1 = 0.f;
                if (cnt <= CAP) {
#pragma unroll 1
                    for (int k = lane; k < cnt; k += 64) {
                        int j = lb[k];
                        float4 d = sjall[colOff + j];
                        float aw = fmaf(cohLoad(&pin[j]), INVK, d.w);
                        float x  = fmaf(qx[r], d.x, fmaf(qy[r], d.y, fmaf(qz[r], d.z, aw)));
                        s1 += fexp2(fminf(x - M[r], 100.f));
                    }
                } else {
#pragma unroll 1
                    for (int c = 0; c < 32; ++c) {
                        int j = c*64 + lane;
                        float4 d = sjall[colOff + j];
                        float aw = fmaf(cohLoad(&pin[j]), INVK, d.w);
                        float x  = fmaf(qx[r], d.x, fmaf(qy[r], d.y, fmaf(qz[r], d.z, aw)));
                        s1 += fexp2(fminf(x - M[r], 100.f));
                    }
                }
                for (int off = 1; off < 64; off <<= 1) s1 += __shfl_xor(s1, off, 64);
                L[r] = M[r] + flog2(fmaxf(s1, 1e-37f));
            }
#pragma unroll
            for (int r = 0; r < RPW; ++r) {
                if (odd) LpG[r] = L[r]; else LpF[r] = L[r];
                if (lane == 0) cohStore(&pout[row0 + r], pc[r] - KS * L[r]);
            }
        } else {
            // ---- dense-type: stage sa, full sweep ----
            for (int t = threadIdx.x; t < NN; t += TPB)
                sa[t] = cohLoad(&pin[t]) * INVK;
            __syncthreads();

            if (pass < ONLINE_PASSES) {
                float m[RPW], s[RPW];
#pragma unroll
                for (int r = 0; r < RPW; ++r) { m[r] = -1e30f; s[r] = 0.f; }
#pragma unroll 2
                for (int c = 0; c < 32; ++c) {
                    float4 d = sjall[colOff + c*64 + lane];
                    float aw = d.w + sa[c*64 + lane];
#pragma unroll
                    for (int r = 0; r < RPW; ++r) {
                        float x  = fmaf(qx[r], d.x, fmaf(qy[r], d.y, fmaf(qz[r], d.z, aw)));
                        float mn = fmaxf(m[r], x);
                        s[r] = fmaf(s[r], fexp2(m[r]-mn), fexp2(x-mn));
                        m[r] = mn;
                    }
                }
#pragma unroll
                for (int r = 0; r < RPW; ++r) {
                    float mm = m[r], sv = s[r];
                    for (int off = 1; off < 64; off <<= 1) {
                        float mo = __shfl_xor(mm, off, 64);
                        float so = __shfl_xor(sv, off, 64);
                        float mn = fmaxf(mm, mo);
                        sv = fmaf(sv, fexp2(mm-mn), so * fexp2(mo-mn));
                        mm = mn;
                    }
                    float L = mm + flog2(fmaxf(sv, 1e-37f));
                    if (odd) LpG[r] = L; else LpF[r] = L;
                    if (lane == 0) cohStore(&pout[row0 + r], pc[r] - KS * L);
                }
            } else {
                // build: dense fixed-shift + register-count compaction
                float s[RPW]; int cn[RPW];
#pragma unroll
                for (int r = 0; r < RPW; ++r) { s[r] = 0.f; cn[r] = 0; }
#pragma unroll 1
                for (int c = 0; c < 32; ++c) {
                    int j = c*64 + lane;
                    float4 d = sjall[colOff + j];
                    float aw = d.w + sa[j];
#pragma unroll
                    for (int r = 0; r < RPW; ++r) {
                        float x = fmaf(qx[r], d.x, fmaf(qy[r], d.y, fmaf(qz[r], d.z, aw)));
                        s[r] += fexp2(fminf(x - M[r], 100.f));
                        bool pred = (x >= M[r] - MARGIN);
                        unsigned long long mask = __ballot((int)pred);
                        if (pred) {
                            int pos = cn[r] + __popcll(mask & ((1ull << lane) - 1ull));
                            if (pos < CAP) slist[odd][rowL0 + r][pos] = (unsigned short)j;
                        }
                        cn[r] += __popcll(mask);   // wave-uniform
                    }
                }
#pragma unroll
                for (int r = 0; r < RPW; ++r) {
                    float sv = s[r];
                    for (int off = 1; off < 64; off <<= 1) sv += __shfl_xor(sv, off, 64);
                    float L = M[r] + flog2(fmaxf(sv, 1e-37f));
                    if (odd) { LpG[r] = L; cnG[r] = cn[r]; }
                    else     { LpF[r] = L; cnF[r] = cn[r]; }
                    if (lane == 0) cohStore(&pout[row0 + r], pc[r] - KS * L);
                }
            }
        }
        barrier_sync(bar, BLOCKS_PER_BATCH * (pass + 1));
    }

    // ---- dis: sum P*C over f-lists (side 0), direct pot loads ----
    {
        float acc[RPW];
#pragma unroll
        for (int r = 0; r < RPW; ++r) acc[r] = 0.f;
#pragma unroll
        for (int r = 0; r < RPW; ++r) {
            const int cnt = cnF[r];
            const unsigned short* lb = slist[0][rowL0 + r];
            const float bb2 = C1K - LpF[r];
            const float pn  = pcf[r] - C1V;    // |p|^2
            float aa = 0.f;
            if (cnt <= CAP) {
#pragma unroll 1
                for (int k = lane; k < cnt; k += 64) {
                    int j = lb[k];
                    float4 d = sjall[j];
                    float aw = fmaf(cohLoad(&gb[j]), INVK, d.w);
                    float dot = fmaf(qxf[r], d.x, fmaf(qyf[r], d.y, qzf[r]*d.z));
                    float y   = dot + aw + bb2;
                    float e   = fexp2(fminf(y, 80.f));
                    aa = fmaf(e, fmaf(-KS, dot, pn - KS*d.w), aa);
                }
            } else {
#pragma unroll 1
                for (int c = 0; c < 32; ++c) {
                    int j = c*64 + lane;
                    float4 d = sjall[j];
                    float aw = fmaf(cohLoad(&gb[j]), INVK, d.w);
                    float dot = fmaf(qxf[r], d.x, fmaf(qyf[r], d.y, qzf[r]*d.z));
                    float y   = dot + aw + bb2;
                    float e   = fexp2(fminf(y, 80.f));
                    aa = fmaf(e, fmaf(-KS, dot, pn - KS*d.w), aa);
                }
            }
            acc[r] = aa;
        }
        float tot = acc[0] + acc[1] + acc[2] + acc[3];
        for (int off = 1; off < 64; off <<= 1) tot += __shfl_xor(tot, off, 64);
        if (lane == 0) wred[wave] = tot;
        __syncthreads();
        if (threadIdx.x == 0) {
            float v = 0.f;
            for (int w = 0; w < 16; ++w) v += wred[w];
            cohStore(&partials[blk], v);
        }
    }

    barrier_sync(gctr, GRID_BLOCKS);

    if (blk == 0) {
        float v = (threadIdx.x < GRID_BLOCKS) ? cohLoad(&partials[threadIdx.x]) : 0.f;
        for (int off = 1; off < 64; off <<= 1) v += __shfl_xor(v, off, 64);
        if (lane == 0) wred[wave] = v;
        __syncthreads();
        if (threadIdx.x == 0) {
            float t2 = 0.f;
            for (int w = 0; w < 16; ++w) t2 += wred[w];
            out[0] = t2 * (1.0f / BB);
        }
    }
}

extern "C" void kernel_launch(void* const* d_in, const int* in_sizes, int n_in,
                              void* d_out, int out_size, void* d_ws, size_t ws_size,
                              hipStream_t stream) {
    const float* preds = (const float*)d_in[0];
    const float* gts   = (const float*)d_in[1];
    float* fp       = (float*)d_ws;
    float* gp       = fp + BB * NN;
    float* partials = gp + BB * NN;
    int*   bctr     = (int*)(partials + GRID_BLOCKS);
    int*   gctr     = bctr + BB * 32;
    float* out      = (float*)d_out;

    size_t zbytes = (size_t)(2 * BB * NN + GRID_BLOCKS) * sizeof(float)
                  + (size_t)(BB * 32 + 32) * sizeof(int);
    hipMemsetAsync(d_ws, 0, zbytes, stream);

    emd_persist<<<dim3(GRID_BLOCKS), dim3(TPB), 0, stream>>>(
        preds, gts, fp, gp, partials, bctr, gctr, out);
}

// Round 18
// 518.595 us; speedup vs baseline: 1.6063x; 1.0521x over previous
//
#include <hip/hip_runtime.h>

// Sinkhorn EMD, B=8, N=2048, eps=0.005, 50 iters.
// R18 = R16 champion (545us, absmax 0.0) minus the mid-course list
// rebuild: builds only at {4,5}. Lists survive 95 passes — drift from
// iter 26..50 is the converged regime (contraction => per-pass movement
// tiny), and MARGIN 48 leaves 24 log2 units (~0.083 potential-units) of
// budget vs measured <<0.01. R17's Jacobi (and R11/R15 fusion) are
// excluded: iteration count is semantic (Jacobi = half-rate GS, failed
// absmax 4.4e-3); the per-pass barrier is load-bearing.
// Structure (all validated): persistent 256x1024, IC-coherent atomics
// no fences (R6), register-resident row state + per-row sparse gathers
// w/ direct IC pot loads (R12), counter barrier (R3), online exact-LSE
// passes 0..3, fixed-shift M = own prev log-sum elsewhere, MARGIN=48,
// CAP=256 (R9/R16).

#define BB 8
#define NN 2048
#define NPASS 100
#define ONLINE_PASSES 4
#define RPW 4
#define GRID_BLOCKS 256
#define BLOCKS_PER_BATCH 32
#define TPB 1024
#define CAP 256
#define MARGIN 48.0f

constexpr float EPSV = 0.005f;
constexpr float KS   = EPSV * 0.69314718055994531f; // eps*ln2
constexpr float INVK = 1.0f / KS;
constexpr float C1V  = -EPSV * 7.6246189861593985f; // eps*log(1/2048)
constexpr float C1K  = C1V * INVK;
constexpr float KQ4  = KS * 0.25f;
constexpr float TWOI = 2.0f * INVK;
constexpr float HK   = KS * 0.5f;

__device__ __forceinline__ float fexp2(float x) { return __builtin_amdgcn_exp2f(x); }
__device__ __forceinline__ float flog2(float x) { return __builtin_amdgcn_logf(x); }

__device__ __forceinline__ float cohLoad(const float* p) {
    return __hip_atomic_load(p, __ATOMIC_RELAXED, __HIP_MEMORY_SCOPE_AGENT);
}
__device__ __forceinline__ void cohStore(float* p, float v) {
    __hip_atomic_store(p, v, __ATOMIC_RELAXED, __HIP_MEMORY_SCOPE_AGENT);
}

__device__ __forceinline__ void barrier_sync(int* ctr, int target) {
    __syncthreads();   // drains vmcnt: all waves' cohStores acked at IC
    if (threadIdx.x == 0) {
        __hip_atomic_fetch_add(ctr, 1, __ATOMIC_RELAXED, __HIP_MEMORY_SCOPE_AGENT);
        while (__hip_atomic_load(ctr, __ATOMIC_RELAXED, __HIP_MEMORY_SCOPE_AGENT) < target) {
            __builtin_amdgcn_s_sleep(1);
        }
    }
    __syncthreads();
}

__global__ void __launch_bounds__(TPB, 4) emd_persist(
    const float* __restrict__ preds, const float* __restrict__ gts,
    float* __restrict__ fpot, float* __restrict__ gpot,
    float* __restrict__ partials, int* __restrict__ bctr, int* __restrict__ gctr,
    float* __restrict__ out)
{
    __shared__ float4 sjall[2 * NN];          // side0=gts, side1=preds
    __shared__ float  sa[NN];                 // staged pots (dense passes only)
    __shared__ float  wred[16];
    __shared__ unsigned short slist[2][64][CAP];

    const int blk  = blockIdx.x;
    const int b    = blk & 7;
    const int rb   = blk >> 3;
    const int wave = threadIdx.x >> 6;
    const int lane = threadIdx.x & 63;
    const int rowL0 = wave * RPW;             // 0..60
    const int row0  = rb * 64 + rowL0;        // global row base for this wave

    const float* pb  = preds + (size_t)b * NN * 3;
    const float* gbp = gts   + (size_t)b * NN * 3;
    float* fb = fpot + (size_t)b * NN;
    float* gb = gpot + (size_t)b * NN;
    int*   bar = bctr + b * 32;

    for (int t = threadIdx.x; t < NN; t += TPB) {
        float gx = gbp[3*t], gy = gbp[3*t+1], gz = gbp[3*t+2];
        float Gx = gx*TWOI, Gy = gy*TWOI, Gz = gz*TWOI;
        sjall[t] = make_float4(Gx, Gy, Gz, -KQ4*(Gx*Gx+Gy*Gy+Gz*Gz));
        float qx = pb[3*t], qy = pb[3*t+1], qz = pb[3*t+2];
        float Qx = qx*TWOI, Qy = qy*TWOI, Qz = qz*TWOI;
        sjall[NN+t] = make_float4(Qx, Qy, Qz, -KQ4*(Qx*Qx+Qy*Qy+Qz*Qz));
    }
    __syncthreads();

    // wave-resident row constants, both sides (loaded ONCE)
    float qxf[RPW], qyf[RPW], qzf[RPW], pcf[RPW];
    float qxg[RPW], qyg[RPW], qzg[RPW], pcg[RPW];
#pragma unroll
    for (int r = 0; r < RPW; ++r) {
        float4 df = sjall[NN + row0 + r];     // preds rows (f side)
        qxf[r] = HK*df.x; qyf[r] = HK*df.y; qzf[r] = HK*df.z;
        pcf[r] = C1V - KS*df.w;
        float4 dg = sjall[row0 + r];          // gts rows (g side)
        qxg[r] = HK*dg.x; qyg[r] = HK*dg.y; qzg[r] = HK*dg.z;
        pcg[r] = C1V - KS*dg.w;
    }
    float LpF[RPW] = {0,0,0,0}, LpG[RPW] = {0,0,0,0};
    int   cnF[RPW] = {0,0,0,0}, cnG[RPW] = {0,0,0,0};

#pragma unroll 1
    for (int pass = 0; pass < NPASS; ++pass) {
        const int odd = pass & 1;
        const int colOff = odd ? NN : 0;
        const float* pin  = odd ? fb : gb;
        float*       pout = odd ? gb : fb;
        const bool isBuild  = (pass == 4) || (pass == 5);
        const bool isSparse = (pass >= ONLINE_PASSES) && !isBuild;

        float qx[RPW], qy[RPW], qz[RPW], pc[RPW], M[RPW];
#pragma unroll
        for (int r = 0; r < RPW; ++r) {
            qx[r] = odd ? qxg[r] : qxf[r];
            qy[r] = odd ? qyg[r] : qyf[r];
            qz[r] = odd ? qzg[r] : qzf[r];
            pc[r] = odd ? pcg[r] : pcf[r];
            M[r]  = odd ? LpG[r] : LpF[r];
        }

        if (isSparse) {
            // ---- sparse: no staging, no intra-pass sync ----
            float L[RPW];
#pragma unroll
            for (int r = 0; r < RPW; ++r) {
                const int cnt = odd ? cnG[r] : cnF[r];
                const unsigned short* lb = slist[odd][rowL0 + r];
                float s1 = 0.f;
                if (cnt <= CAP) {
#pragma unroll 1
                    for (int k = lane; k < cnt; k += 64) {
                        int j = lb[k];
                        float4 d = sjall[colOff + j];
                        float aw = fmaf(cohLoad(&pin[j]), INVK, d.w);
                        float x  = fmaf(qx[r], d.x, fmaf(qy[r], d.y, fmaf(qz[r], d.z, aw)));
                        s1 += fexp2(fminf(x - M[r], 100.f));
                    }
                } else {
#pragma unroll 1
                    for (int c = 0; c < 32; ++c) {
                        int j = c*64 + lane;
                        float4 d = sjall[colOff + j];
                        float aw = fmaf(cohLoad(&pin[j]), INVK, d.w);
                        float x  = fmaf(qx[r], d.x, fmaf(qy[r], d.y, fmaf(qz[r], d.z, aw)));
                        s1 += fexp2(fminf(x - M[r], 100.f));
                    }
                }
                for (int off = 1; off < 64; off <<= 1) s1 += __shfl_xor(s1, off, 64);
                L[r] = M[r] + flog2(fmaxf(s1, 1e-37f));
            }
#pragma unroll
            for (int r = 0; r < RPW; ++r) {
                if (odd) LpG[r] = L[r]; else LpF[r] = L[r];
                if (lane == 0) cohStore(&pout[row0 + r], pc[r] - KS * L[r]);
            }
        } else {
            // ---- dense-type: stage sa, full sweep ----
            for (int t = threadIdx.x; t < NN; t += TPB)
                sa[t] = cohLoad(&pin[t]) * INVK;
            __syncthreads();

            if (pass < ONLINE_PASSES) {
                float m[RPW], s[RPW];
#pragma unroll
                for (int r = 0; r < RPW; ++r) { m[r] = -1e30f; s[r] = 0.f; }
#pragma unroll 2
                for (int c = 0; c < 32; ++c) {
                    float4 d = sjall[colOff + c*64 + lane];
                    float aw = d.w + sa[c*64 + lane];
#pragma unroll
                    for (int r = 0; r < RPW; ++r) {
                        float x  = fmaf(qx[r], d.x, fmaf(qy[r], d.y, fmaf(qz[r], d.z, aw)));
                        float mn = fmaxf(m[r], x);
                        s[r] = fmaf(s[r], fexp2(m[r]-mn), fexp2(x-mn));
                        m[r] = mn;
                    }
                }
#pragma unroll
                for (int r = 0; r < RPW; ++r) {
                    float mm = m[r], sv = s[r];
                    for (int off = 1; off < 64; off <<= 1) {
                        float mo = __shfl_xor(mm, off, 64);
                        float so = __shfl_xor(sv, off, 64);
                        float mn = fmaxf(mm, mo);
                        sv = fmaf(sv, fexp2(mm-mn), so * fexp2(mo-mn));
                        mm = mn;
                    }
                    float L = mm + flog2(fmaxf(sv, 1e-37f));
                    if (odd) LpG[r] = L; else LpF[r] = L;
                    if (lane == 0) cohStore(&pout[row0 + r], pc[r] - KS * L);
                }
            } else {
                // build: dense fixed-shift + register-count compaction
                float s[RPW]; int cn[RPW];
#pragma unroll
                for (int r = 0; r < RPW; ++r) { s[r] = 0.f; cn[r] = 0; }
#pragma unroll 1
                for (int c = 0; c < 32; ++c) {
                    int j = c*64 + lane;
                    float4 d = sjall[colOff + j];
                    float aw = d.w + sa[j];
#pragma unroll
                    for (int r = 0; r < RPW; ++r) {
                        float x = fmaf(qx[r], d.x, fmaf(qy[r], d.y, fmaf(qz[r], d.z, aw)));
                        s[r] += fexp2(fminf(x - M[r], 100.f));
                        bool pred = (x >= M[r] - MARGIN);
                        unsigned long long mask = __ballot((int)pred);
                        if (pred) {
                            int pos = cn[r] + __popcll(mask & ((1ull << lane) - 1ull));
                            if (pos < CAP) slist[odd][rowL0 + r][pos] = (unsigned short)j;
                        }
                        cn[r] += __popcll(mask);   // wave-uniform
                    }
                }
#pragma unroll
                for (int r = 0; r < RPW; ++r) {
                    float sv = s[r];
                    for (int off = 1; off < 64; off <<= 1) sv += __shfl_xor(sv, off, 64);
                    float L = M[r] + flog2(fmaxf(sv, 1e-37f));
                    if (odd) { LpG[r] = L; cnG[r] = cn[r]; }
                    else     { LpF[r] = L; cnF[r] = cn[r]; }
                    if (lane == 0) cohStore(&pout[row0 + r], pc[r] - KS * L);
                }
            }
        }
        barrier_sync(bar, BLOCKS_PER_BATCH * (pass + 1));
    }

    // ---- dis: sum P*C over f-lists (side 0), direct pot loads ----
    {
        float acc[RPW];
#pragma unroll
        for (int r = 0; r < RPW; ++r) acc[r] = 0.f;
#pragma unroll
        for (int r = 0; r < RPW; ++r) {
            const int cnt = cnF[r];
            const unsigned short* lb = slist[0][rowL0 + r];
            const float bb2 = C1K - LpF[r];
            const float pn  = pcf[r] - C1V;    // |p|^2
            float aa = 0.f;
            if (cnt <= CAP) {
#pragma unroll 1
                for (int k = lane; k < cnt; k += 64) {
                    int j = lb[k];
                    float4 d = sjall[j];
                    float aw = fmaf(cohLoad(&gb[j]), INVK, d.w);
                    float dot = fmaf(qxf[r], d.x, fmaf(qyf[r], d.y, qzf[r]*d.z));
                    float y   = dot + aw + bb2;
                    float e   = fexp2(fminf(y, 80.f));
                    aa = fmaf(e, fmaf(-KS, dot, pn - KS*d.w), aa);
                }
            } else {
#pragma unroll 1
                for (int c = 0; c < 32; ++c) {
                    int j = c*64 + lane;
                    float4 d = sjall[j];
                    float aw = fmaf(cohLoad(&gb[j]), INVK, d.w);
                    float dot = fmaf(qxf[r], d.x, fmaf(qyf[r], d.y, qzf[r]*d.z));
                    float y   = dot + aw + bb2;
                    float e   = fexp2(fminf(y, 80.f));
                    aa = fmaf(e, fmaf(-KS, dot, pn - KS*d.w), aa);
                }
            }
            acc[r] = aa;
        }
        float tot = acc[0] + acc[1] + acc[2] + acc[3];
        for (int off = 1; off < 64; off <<= 1) tot += __shfl_xor(tot, off, 64);
        if (lane == 0) wred[wave] = tot;
        __syncthreads();
        if (threadIdx.x == 0) {
            float v = 0.f;
            for (int w = 0; w < 16; ++w) v += wred[w];
            cohStore(&partials[blk], v);
        }
    }

    barrier_sync(gctr, GRID_BLOCKS);

    if (blk == 0) {
        float v = (threadIdx.x < GRID_BLOCKS) ? cohLoad(&partials[threadIdx.x]) : 0.f;
        for (int off = 1; off < 64; off <<= 1) v += __shfl_xor(v, off, 64);
        if (lane == 0) wred[wave] = v;
        __syncthreads();
        if (threadIdx.x == 0) {
            float t2 = 0.f;
            for (int w = 0; w < 16; ++w) t2 += wred[w];
            out[0] = t2 * (1.0f / BB);
        }
    }
}

extern "C" void kernel_launch(void* const* d_in, const int* in_sizes, int n_in,
                              void* d_out, int out_size, void* d_ws, size_t ws_size,
                              hipStream_t stream) {
    const float* preds = (const float*)d_in[0];
    const float* gts   = (const float*)d_in[1];
    float* fp       = (float*)d_ws;
    float* gp       = fp + BB * NN;
    float* partials = gp + BB * NN;
    int*   bctr     = (int*)(partials + GRID_BLOCKS);
    int*   gctr     = bctr + BB * 32;
    float* out      = (float*)d_out;

    size_t zbytes = (size_t)(2 * BB * NN + GRID_BLOCKS) * sizeof(float)
                  + (size_t)(BB * 32 + 32) * sizeof(int);
    hipMemsetAsync(d_ws, 0, zbytes, stream);

    emd_persist<<<dim3(GRID_BLOCKS), dim3(TPB), 0, stream>>>(
        preds, gts, fp, gp, partials, bctr, gctr, out);
}